// Round 1
// baseline (137.580 us; speedup 1.0000x reference)
//
#include <hip/hip_runtime.h>
#include <hip/hip_bf16.h>

#define N_ATOMS 400000
#define N_BLOCKS 50000
#define BATCHES 64
#define CCH 4
#define AX 3
#define DH 128
#define NRBF 16

// Workspace float layout
#define ACC_OFF 0          // B*17 : [cnt, zsum[12], zsq[4]] per batch
#define ZC_OFF  1088       // B*12
#define RS_OFF  1856       // B*4
#define HB_OFF  2112       // B*128

__device__ __forceinline__ float silu_f(float x) { return x / (1.f + expf(-x)); }

// ---------------- Kernel 1: per-batch stats (cnt, Zsum, Zsqsum) ----------------
__global__ __launch_bounds__(256) void k1_stats(
    const float* __restrict__ Z, const int* __restrict__ block_id,
    const int* __restrict__ batch_id, float* __restrict__ acc) {
  __shared__ float bins[BATCHES * 17];
  for (int i = threadIdx.x; i < BATCHES * 17; i += 256) bins[i] = 0.f;
  __syncthreads();

  const float4* Z4 = (const float4*)Z;
  int base = blockIdx.x * 1024;

  for (int it = 0; it < 4; ++it) {
    int n = base + it * 256 + threadIdx.x;
    int uid = -1;
    float z[12];
#pragma unroll
    for (int j = 0; j < 12; ++j) z[j] = 0.f;
    if (n < N_ATOMS) {
      uid = batch_id[block_id[n]];
      float4 a = Z4[n * 3 + 0], b = Z4[n * 3 + 1], c = Z4[n * 3 + 2];
      z[0] = a.x; z[1] = a.y; z[2]  = a.z; z[3]  = a.w;
      z[4] = b.x; z[5] = b.y; z[6]  = b.z; z[7]  = b.w;
      z[8] = c.x; z[9] = c.y; z[10] = c.z; z[11] = c.w;
    }
    // contiguous uid range present in this wave (sorted input -> tiny range)
    int lo = (uid < 0) ? 0x7fffffff : uid;
    int hi = uid;
#pragma unroll
    for (int m = 32; m; m >>= 1) {
      lo = min(lo, __shfl_xor(lo, m));
      hi = max(hi, __shfl_xor(hi, m));
    }
    if (hi < 0) continue;  // wave-uniform: no valid atoms

    for (int u = lo; u <= hi; ++u) {
      bool mine = (uid == u);
      unsigned long long mb = __ballot(mine);
      float vals[16];
#pragma unroll
      for (int j = 0; j < 12; ++j) vals[j] = mine ? z[j] : 0.f;
#pragma unroll
      for (int c = 0; c < 4; ++c)
        vals[12 + c] = mine ? (z[c*3]*z[c*3] + z[c*3+1]*z[c*3+1] + z[c*3+2]*z[c*3+2]) : 0.f;
#pragma unroll
      for (int v = 0; v < 16; ++v) {
        float x = vals[v];
#pragma unroll
        for (int m = 32; m; m >>= 1) x += __shfl_xor(x, m);
        vals[v] = x;
      }
      if ((threadIdx.x & 63) == 0) {
        atomicAdd(&bins[u * 17 + 0], (float)__popcll(mb));
#pragma unroll
        for (int v = 0; v < 16; ++v) atomicAdd(&bins[u * 17 + 1 + v], vals[v]);
      }
    }
  }
  __syncthreads();
  for (int i = threadIdx.x; i < BATCHES * 17; i += 256) {
    float v = bins[i];
    if (v != 0.f) atomicAdd(&acc[i], v);
  }
}

// ---------------- Kernel 2: rescale + RBF + 2-layer MLP (per batch row) ----------------
__global__ __launch_bounds__(128) void k2_mlp(
    const float* __restrict__ sigma, const float* __restrict__ W1,
    const float* __restrict__ b1, const float* __restrict__ W2,
    const float* __restrict__ b2, const float* __restrict__ acc,
    float* __restrict__ Zc, float* __restrict__ resc,
    float* __restrict__ hbuf, float* __restrict__ resc_out) {
  int b = blockIdx.x, t = threadIdx.x;
  __shared__ float rbf_s[64];
  __shared__ float h1_s[128];
  __shared__ float resc_s[4];

  if (t < 4) {
    int c = t;
    float cnt = acc[b * 17];
    float cs = fmaxf(cnt, 1.f);
    float s2 = 0.f;
#pragma unroll
    for (int a = 0; a < 3; ++a) {
      float zc = acc[b * 17 + 1 + c * 3 + a] / cs;
      Zc[b * 12 + c * 3 + a] = zc;
      s2 += zc * zc;
    }
    float sq = acc[b * 17 + 13 + c] - cnt * s2;
    float denom = fmaxf(cnt * 3.f - 1.f, 1.f);
    float var = fmaxf(sq / denom, 0.f);
    float r = sigma[c] / sqrtf(var);
    resc_s[c] = r;
    resc[b * 4 + c] = r;
    resc_out[b * 4 + c] = r;
  }
  __syncthreads();
  if (t < 64) {
    int c = t >> 4, ri = t & 15;
    float ds = resc_s[c] * (1.f / 7.f);
    float env = 0.f;
    if (ds < 1.f) {
      float d2 = ds * ds;
      float d5 = d2 * d2 * ds;
      env = 1.f - 21.f * d5 + 35.f * d5 * ds - 15.f * d5 * d2;
    }
    float off = (float)ri * (1.f / 15.f);
    float dd = ds - off;
    rbf_s[t] = env * expf(-112.5f * dd * dd);
  }
  __syncthreads();
  float s = b1[t];
#pragma unroll 8
  for (int k = 0; k < 64; ++k) s += rbf_s[k] * W1[k * 128 + t];
  h1_s[t] = silu_f(s);
  __syncthreads();
  float s2 = b2[t];
#pragma unroll 8
  for (int k = 0; k < 128; ++k) s2 += h1_s[k] * W2[k * 128 + t];
  hbuf[b * 128 + t] = silu_f(s2);
}

// ---------------- Kernel 3: per-atom apply (Z out + H add + LayerNorm) ----------------
__global__ __launch_bounds__(256) void k3_apply(
    const float* __restrict__ H, const float* __restrict__ Z,
    const int* __restrict__ block_id, const int* __restrict__ batch_id,
    const float* __restrict__ ln_w, const float* __restrict__ ln_b,
    const float* __restrict__ Zc, const float* __restrict__ resc,
    const float* __restrict__ hbuf,
    float* __restrict__ Hout, float* __restrict__ Zout) {
  int g = threadIdx.x >> 5, lane = threadIdx.x & 31;
  int n = blockIdx.x * 8 + g;
  int uid = batch_id[block_id[n]];

  const float4* H4 = (const float4*)H;
  const float4* HB4 = (const float4*)hbuf;
  float4 v = H4[(size_t)n * 32 + lane];
  float4 hb = HB4[uid * 32 + lane];
  float x0 = v.x + hb.x, x1 = v.y + hb.y, x2 = v.z + hb.z, x3 = v.w + hb.w;
  float s = x0 + x1 + x2 + x3;
  float q = x0 * x0 + x1 * x1 + x2 * x2 + x3 * x3;
#pragma unroll
  for (int m = 1; m < 32; m <<= 1) {
    s += __shfl_xor(s, m);
    q += __shfl_xor(q, m);
  }
  float mean = s * (1.f / 128.f);
  float var = q * (1.f / 128.f) - mean * mean;
  float inv = rsqrtf(var + 1e-5f);
  const float4* LW4 = (const float4*)ln_w;
  const float4* LB4 = (const float4*)ln_b;
  float4 w = LW4[lane], bb = LB4[lane];
  float4 o;
  o.x = (x0 - mean) * inv * w.x + bb.x;
  o.y = (x1 - mean) * inv * w.y + bb.y;
  o.z = (x2 - mean) * inv * w.z + bb.z;
  o.w = (x3 - mean) * inv * w.w + bb.w;
  ((float4*)Hout)[(size_t)n * 32 + lane] = o;

  if (lane < 3) {
    const float4* Z4 = (const float4*)Z;
    float4 z = Z4[n * 3 + lane];
    float zz[4] = {z.x, z.y, z.z, z.w};
    float oo[4];
#pragma unroll
    for (int k = 0; k < 4; ++k) {
      int j = lane * 4 + k;
      int c = j / 3;
      float zcv = Zc[uid * 12 + j];
      float r = resc[uid * 4 + c];
      oo[k] = zcv + (zz[k] - zcv) * r;
    }
    ((float4*)Zout)[n * 3 + lane] = make_float4(oo[0], oo[1], oo[2], oo[3]);
  }
}

extern "C" void kernel_launch(void* const* d_in, const int* in_sizes, int n_in,
                              void* d_out, int out_size, void* d_ws, size_t ws_size,
                              hipStream_t stream) {
  const float* H     = (const float*)d_in[0];
  const float* Z     = (const float*)d_in[1];
  const float* sigma = (const float*)d_in[2];
  const float* W1    = (const float*)d_in[3];
  const float* b1    = (const float*)d_in[4];
  const float* W2    = (const float*)d_in[5];
  const float* b2    = (const float*)d_in[6];
  const float* ln_w  = (const float*)d_in[7];
  const float* ln_b  = (const float*)d_in[8];
  const int* block_id = (const int*)d_in[9];
  const int* batch_id = (const int*)d_in[10];

  float* ws   = (float*)d_ws;
  float* acc  = ws + ACC_OFF;
  float* Zc   = ws + ZC_OFF;
  float* resc = ws + RS_OFF;
  float* hbuf = ws + HB_OFF;

  float* Hout = (float*)d_out;
  float* Zout = Hout + (size_t)N_ATOMS * DH;
  float* resc_out = Zout + (size_t)N_ATOMS * CCH * AX;

  hipMemsetAsync(acc, 0, BATCHES * 17 * sizeof(float), stream);
  k1_stats<<<(N_ATOMS + 1023) / 1024, 256, 0, stream>>>(Z, block_id, batch_id, acc);
  k2_mlp<<<BATCHES, 128, 0, stream>>>(sigma, W1, b1, W2, b2, acc, Zc, resc, hbuf, resc_out);
  k3_apply<<<N_ATOMS / 8, 256, 0, stream>>>(H, Z, block_id, batch_id, ln_w, ln_b,
                                            Zc, resc, hbuf, Hout, Zout);
}

// Round 2
// 104.207 us; speedup vs baseline: 1.3203x; 1.3203x over previous
//
#include <hip/hip_runtime.h>
#include <hip/hip_bf16.h>

#define N_ATOMS 400000
#define N_BLOCKS 50000
#define BATCHES 64
#define CCH 4
#define AX 3
#define DH 128
#define NRBF 16

// Workspace float layout
#define ACC_OFF 0          // B*17 : [cnt, zsum[12], zsq[4]] per batch
#define ZC_OFF  1088       // B*12
#define RS_OFF  1856       // B*4
#define HB_OFF  2112       // B*128
#define UID_OFF 10304      // N_ATOMS bytes (as uint8), starts at float offset 10304

typedef float f4 __attribute__((ext_vector_type(4)));

__device__ __forceinline__ f4 ntload4(const f4* p) { return __builtin_nontemporal_load(p); }
__device__ __forceinline__ void ntstore4(f4* p, f4 v) { __builtin_nontemporal_store(v, p); }
__device__ __forceinline__ float silu_f(float x) { return x / (1.f + expf(-x)); }

// ---------------- Kernel 1: per-batch stats (cnt, Zsum, Zsqsum) + uid8 ----------------
__global__ __launch_bounds__(256) void k1_stats(
    const float* __restrict__ Z, const int* __restrict__ block_id,
    const int* __restrict__ batch_id, float* __restrict__ acc,
    unsigned char* __restrict__ uid8) {
  __shared__ float bins[BATCHES * 17];
  for (int i = threadIdx.x; i < BATCHES * 17; i += 256) bins[i] = 0.f;
  __syncthreads();

  const f4* Z4 = (const f4*)Z;
  int n = blockIdx.x * 256 + threadIdx.x;
  bool valid = (n < N_ATOMS);
  int uid = -1;
  float z[12];
#pragma unroll
  for (int j = 0; j < 12; ++j) z[j] = 0.f;
  if (valid) {
    uid = batch_id[block_id[n]];
    uid8[n] = (unsigned char)uid;
    f4 a = ntload4(&Z4[n * 3 + 0]);
    f4 b = ntload4(&Z4[n * 3 + 1]);
    f4 c = ntload4(&Z4[n * 3 + 2]);
    z[0] = a.x; z[1] = a.y; z[2]  = a.z; z[3]  = a.w;
    z[4] = b.x; z[5] = b.y; z[6]  = b.z; z[7]  = b.w;
    z[8] = c.x; z[9] = c.y; z[10] = c.z; z[11] = c.w;
  }

  int lo = valid ? uid : 0x7fffffff;
  int hi = uid;
#pragma unroll
  for (int m = 32; m; m >>= 1) {
    lo = min(lo, __shfl_xor(lo, m));
    hi = max(hi, __shfl_xor(hi, m));
  }

  if (lo == hi) {
    // wave-uniform uid (the common case: sorted input)
    float vals[16];
#pragma unroll
    for (int j = 0; j < 12; ++j) vals[j] = z[j];
#pragma unroll
    for (int c = 0; c < 4; ++c)
      vals[12 + c] = z[c*3]*z[c*3] + z[c*3+1]*z[c*3+1] + z[c*3+2]*z[c*3+2];
#pragma unroll
    for (int v = 0; v < 16; ++v) {
      float x = vals[v];
#pragma unroll
      for (int m = 32; m; m >>= 1) x += __shfl_xor(x, m);
      vals[v] = x;
    }
    unsigned long long mb = __ballot(valid);
    if ((threadIdx.x & 63) == 0) {
      atomicAdd(&bins[hi * 17 + 0], (float)__popcll(mb));
#pragma unroll
      for (int v = 0; v < 16; ++v) atomicAdd(&bins[hi * 17 + 1 + v], vals[v]);
    }
  } else if (hi >= 0) {
    // rare: wave straddles a batch boundary -> per-lane LDS atomics
    if (valid) {
      atomicAdd(&bins[uid * 17 + 0], 1.f);
#pragma unroll
      for (int j = 0; j < 12; ++j) atomicAdd(&bins[uid * 17 + 1 + j], z[j]);
#pragma unroll
      for (int c = 0; c < 4; ++c)
        atomicAdd(&bins[uid * 17 + 13 + c],
                  z[c*3]*z[c*3] + z[c*3+1]*z[c*3+1] + z[c*3+2]*z[c*3+2]);
    }
  }
  __syncthreads();
  for (int i = threadIdx.x; i < BATCHES * 17; i += 256) {
    float v = bins[i];
    if (v != 0.f) atomicAdd(&acc[i], v);
  }
}

// ---------------- Kernel 2: rescale + RBF + 2-layer MLP (per batch row) ----------------
__global__ __launch_bounds__(128) void k2_mlp(
    const float* __restrict__ sigma, const float* __restrict__ W1,
    const float* __restrict__ b1, const float* __restrict__ W2,
    const float* __restrict__ b2, const float* __restrict__ acc,
    float* __restrict__ Zc, float* __restrict__ resc,
    float* __restrict__ hbuf, float* __restrict__ resc_out) {
  int b = blockIdx.x, t = threadIdx.x;
  __shared__ float rbf_s[64];
  __shared__ float h1_s[128];
  __shared__ float resc_s[4];

  if (t < 4) {
    int c = t;
    float cnt = acc[b * 17];
    float cs = fmaxf(cnt, 1.f);
    float s2 = 0.f;
#pragma unroll
    for (int a = 0; a < 3; ++a) {
      float zc = acc[b * 17 + 1 + c * 3 + a] / cs;
      Zc[b * 12 + c * 3 + a] = zc;
      s2 += zc * zc;
    }
    float sq = acc[b * 17 + 13 + c] - cnt * s2;
    float denom = fmaxf(cnt * 3.f - 1.f, 1.f);
    float var = fmaxf(sq / denom, 0.f);
    float r = sigma[c] / sqrtf(var);
    resc_s[c] = r;
    resc[b * 4 + c] = r;
    resc_out[b * 4 + c] = r;
  }
  __syncthreads();
  if (t < 64) {
    int c = t >> 4, ri = t & 15;
    float ds = resc_s[c] * (1.f / 7.f);
    float env = 0.f;
    if (ds < 1.f) {
      float d2 = ds * ds;
      float d5 = d2 * d2 * ds;
      env = 1.f - 21.f * d5 + 35.f * d5 * ds - 15.f * d5 * d2;
    }
    float off = (float)ri * (1.f / 15.f);
    float dd = ds - off;
    rbf_s[t] = env * expf(-112.5f * dd * dd);
  }
  __syncthreads();
  float s = b1[t];
#pragma unroll 8
  for (int k = 0; k < 64; ++k) s += rbf_s[k] * W1[k * 128 + t];
  h1_s[t] = silu_f(s);
  __syncthreads();
  float s2 = b2[t];
#pragma unroll 8
  for (int k = 0; k < 128; ++k) s2 += h1_s[k] * W2[k * 128 + t];
  hbuf[b * 128 + t] = silu_f(s2);
}

// ---------------- Kernel 3: per-atom apply (Z out + H add + LayerNorm) ----------------
// 16 atoms per 256-thread block; each 32-lane group handles 2 atoms.
__global__ __launch_bounds__(256) void k3_apply(
    const float* __restrict__ H, const float* __restrict__ Z,
    const unsigned char* __restrict__ uid8,
    const float* __restrict__ ln_w, const float* __restrict__ ln_b,
    const float* __restrict__ Zc, const float* __restrict__ resc,
    const float* __restrict__ hbuf,
    float* __restrict__ Hout, float* __restrict__ Zout) {
  int g = threadIdx.x >> 5, lane = threadIdx.x & 31;
  int n0 = blockIdx.x * 16 + g * 2;
  int n1 = n0 + 1;

  int uid0 = uid8[n0];
  int uid1 = uid8[n1];

  const f4* H4 = (const f4*)H;
  const f4* HB4 = (const f4*)hbuf;
  f4 v0 = ntload4(&H4[(size_t)n0 * 32 + lane]);
  f4 v1 = ntload4(&H4[(size_t)n1 * 32 + lane]);
  f4 hb0 = HB4[uid0 * 32 + lane];
  f4 hb1 = HB4[uid1 * 32 + lane];

  f4 x0 = v0 + hb0;
  f4 x1 = v1 + hb1;

  float s0 = x0.x + x0.y + x0.z + x0.w;
  float q0 = x0.x*x0.x + x0.y*x0.y + x0.z*x0.z + x0.w*x0.w;
  float s1 = x1.x + x1.y + x1.z + x1.w;
  float q1 = x1.x*x1.x + x1.y*x1.y + x1.z*x1.z + x1.w*x1.w;
#pragma unroll
  for (int m = 1; m < 32; m <<= 1) {
    s0 += __shfl_xor(s0, m);
    q0 += __shfl_xor(q0, m);
    s1 += __shfl_xor(s1, m);
    q1 += __shfl_xor(q1, m);
  }
  float mean0 = s0 * (1.f / 128.f);
  float inv0 = rsqrtf(q0 * (1.f / 128.f) - mean0 * mean0 + 1e-5f);
  float mean1 = s1 * (1.f / 128.f);
  float inv1 = rsqrtf(q1 * (1.f / 128.f) - mean1 * mean1 + 1e-5f);

  const f4* LW4 = (const f4*)ln_w;
  const f4* LB4 = (const f4*)ln_b;
  f4 w = LW4[lane], bb = LB4[lane];
  f4 o0, o1;
  o0.x = (x0.x - mean0) * inv0 * w.x + bb.x;
  o0.y = (x0.y - mean0) * inv0 * w.y + bb.y;
  o0.z = (x0.z - mean0) * inv0 * w.z + bb.z;
  o0.w = (x0.w - mean0) * inv0 * w.w + bb.w;
  o1.x = (x1.x - mean1) * inv1 * w.x + bb.x;
  o1.y = (x1.y - mean1) * inv1 * w.y + bb.y;
  o1.z = (x1.z - mean1) * inv1 * w.z + bb.z;
  o1.w = (x1.w - mean1) * inv1 * w.w + bb.w;
  ntstore4(&((f4*)Hout)[(size_t)n0 * 32 + lane], o0);
  ntstore4(&((f4*)Hout)[(size_t)n1 * 32 + lane], o1);

  // Z path: lanes 0..2 handle atom n0, lanes 3..5 handle atom n1
  if (lane < 6) {
    int a = (lane >= 3) ? 1 : 0;
    int comp = lane - a * 3;
    int n = n0 + a;
    int uid = a ? uid1 : uid0;
    const f4* Z4 = (const f4*)Z;
    f4 z = ntload4(&Z4[n * 3 + comp]);
    float zz[4] = {z.x, z.y, z.z, z.w};
    float oo[4];
#pragma unroll
    for (int k = 0; k < 4; ++k) {
      int j = comp * 4 + k;
      int c = j / 3;
      float zcv = Zc[uid * 12 + j];
      float r = resc[uid * 4 + c];
      oo[k] = zcv + (zz[k] - zcv) * r;
    }
    f4 ov = {oo[0], oo[1], oo[2], oo[3]};
    ntstore4(&((f4*)Zout)[n * 3 + comp], ov);
  }
}

extern "C" void kernel_launch(void* const* d_in, const int* in_sizes, int n_in,
                              void* d_out, int out_size, void* d_ws, size_t ws_size,
                              hipStream_t stream) {
  const float* H     = (const float*)d_in[0];
  const float* Z     = (const float*)d_in[1];
  const float* sigma = (const float*)d_in[2];
  const float* W1    = (const float*)d_in[3];
  const float* b1    = (const float*)d_in[4];
  const float* W2    = (const float*)d_in[5];
  const float* b2    = (const float*)d_in[6];
  const float* ln_w  = (const float*)d_in[7];
  const float* ln_b  = (const float*)d_in[8];
  const int* block_id = (const int*)d_in[9];
  const int* batch_id = (const int*)d_in[10];

  float* ws   = (float*)d_ws;
  float* acc  = ws + ACC_OFF;
  float* Zc   = ws + ZC_OFF;
  float* resc = ws + RS_OFF;
  float* hbuf = ws + HB_OFF;
  unsigned char* uid8 = (unsigned char*)(ws + UID_OFF);

  float* Hout = (float*)d_out;
  float* Zout = Hout + (size_t)N_ATOMS * DH;
  float* resc_out = Zout + (size_t)N_ATOMS * CCH * AX;

  hipMemsetAsync(acc, 0, BATCHES * 17 * sizeof(float), stream);
  k1_stats<<<(N_ATOMS + 255) / 256, 256, 0, stream>>>(Z, block_id, batch_id, acc, uid8);
  k2_mlp<<<BATCHES, 128, 0, stream>>>(sigma, W1, b1, W2, b2, acc, Zc, resc, hbuf, resc_out);
  k3_apply<<<N_ATOMS / 16, 256, 0, stream>>>(H, Z, uid8, ln_w, ln_b,
                                             Zc, resc, hbuf, Hout, Zout);
}